// Round 9
// baseline (825.797 us; speedup 1.0000x reference)
//
#include <hip/hip_runtime.h>
#include <stdint.h>
#include <stddef.h>

#define NCH   256
#define EDIM  64
#define HDIM  128
#define G3    384
#define BATCH 128
#define WRD   64
#define CLEN  48
#define NW    8192
#define OUTD  8

#define LOG2E 1.44269504088896f

// ---- canonical fp32 weight offsets (element units) ----
#define C_EMB     0
#define C_CWIH_F  16384
#define C_CWHH_F  40960
#define C_CBIH_F  90112
#define C_CBHH_F  90496
#define C_CWIH_B  90880
#define C_CWHH_B  115456
#define C_CBIH_B  164608
#define C_CBHH_B  164992
#define C_MWIH_F  165376
#define C_MWHH_F  263680
#define C_MBIH_F  312832
#define C_MBHH_F  313600
#define C_MWIH_B  314368
#define C_MWHH_B  412672
#define C_MBIH_B  461824
#define C_MBHH_B  462592
#define C_WWP     463360
#define C_WBP     496128
#define C_WCTX    496256
#define C_PWP     496384
#define C_PBP     529152
#define C_PCTX    529280
#define C_WOUT    529408
#define C_BOUT    531456
#define C_TOTAL   531464

// ---- ws byte offsets ----
#define OFF_FLAG    0u
#define OFF_CANON   1024u
#define OFF_WPFRAG  (4u*1024u*1024u)               // 32768 f16 = 64 KB
#define OFF_PFRAG   (4u*1024u*1024u + 65536u)      // 32768 f16 = 64 KB
#define OFF_MFRAG   (4u*1024u*1024u + 131072u)     // 196608 f16 = 384 KB
#define OFF_BIASV   (4u*1024u*1024u + 524288u)     // 768 f32 + L0 at [768]
#define OFF_ORD     (4u*1024u*1024u + 532480u)     // 8192 int = 32 KB
#define OFF_XGT4    5111808u                        // 65536 float4 = 1 MB
#define OFF_WORDS   35651584u                       // 8192*256 f16 = 4 MB
#define OFF_MSGOUT  47185920u
#define OFF_CHOUT   54525952u                       // of only: 8192*48*128 f16 = 100 MB

typedef _Float16 h2v __attribute__((ext_vector_type(2)));
typedef _Float16 f16x8 __attribute__((ext_vector_type(8)));
typedef float f32x4 __attribute__((ext_vector_type(4)));

__device__ __forceinline__ float bf16_to_f32(unsigned short u){
  union{unsigned int i;float f;}v; v.i=((unsigned int)u)<<16; return v.f;
}
__device__ __forceinline__ unsigned short f32_to_bf16(float f){
  union{float f;unsigned int i;}v; v.f=f;
  unsigned int u=v.i; unsigned int r=(u + 0x7fffu + ((u>>16)&1u))>>16;
  return (unsigned short)r;
}
__device__ __forceinline__ uint32_t pack_h2(float x,float y){
  h2v h; h[0]=(_Float16)x; h[1]=(_Float16)y; uint32_t u; __builtin_memcpy(&u,&h,4); return u;
}
__device__ __forceinline__ unsigned short f32_to_h16u(float f){
  _Float16 h=(_Float16)f; unsigned short u; __builtin_memcpy(&u,&h,2); return u;
}
__device__ __forceinline__ float dot2(uint32_t a, uint32_t b, float c){
#if __has_builtin(__builtin_amdgcn_fdot2)
  h2v av,bv; __builtin_memcpy(&av,&a,4); __builtin_memcpy(&bv,&b,4);
  return __builtin_amdgcn_fdot2(av,bv,c,false);
#else
  h2v av,bv; __builtin_memcpy(&av,&a,4); __builtin_memcpy(&bv,&b,4);
  return c + (float)av[0]*(float)bv[0] + (float)av[1]*(float)bv[1];
#endif
}
__device__ __forceinline__ float exp2_fast(float x){
#if __has_builtin(__builtin_amdgcn_exp2f)
  return __builtin_amdgcn_exp2f(x);
#else
  return exp2f(x);
#endif
}
__device__ __forceinline__ float rcp_fast(float x){
#if __has_builtin(__builtin_amdgcn_rcpf)
  return __builtin_amdgcn_rcpf(x);
#else
  return 1.f/x;
#endif
}
// sigmoid(x) given s = -log2e*x ; tanh(y) given u = 2*log2e*y
__device__ __forceinline__ float sig2(float s){ return rcp_fast(1.f+exp2_fast(s)); }
__device__ __forceinline__ float tanh2(float u){ return fmaf(-2.f, rcp_fast(exp2_fast(u)+1.f), 1.f); }
__device__ __forceinline__ float wave_sum(float v){
  #pragma unroll
  for(int m=32;m>=1;m>>=1) v += __shfl_xor(v,m,64);
  return v;
}
__device__ __forceinline__ float wave_max(float v){
  #pragma unroll
  for(int m=32;m>=1;m>>=1) v = fmaxf(v,__shfl_xor(v,m,64));
  return v;
}
__device__ __forceinline__ f32x4 mfma16(f16x8 a, f16x8 b, f32x4 c){
  return __builtin_amdgcn_mfma_f32_16x16x32_f16(a, b, c, 0, 0, 0);
}

struct ConvArgs { const void* src[25]; int len[25]; int off[25]; };

// ---------- convert with inline dtype sniff ----------
__global__ void k_convert(ConvArgs a, int* __restrict__ flag, float* __restrict__ dst){
  const unsigned short* u=(const unsigned short*)a.src[0];
  int found=0;
  for(int i=threadIdx.x;i<2048;i+=256){ float v=bf16_to_f32(u[i]); if(fabsf(v)>8.f) found=1; }
  __shared__ int s;
  if(threadIdx.x==0) s=0;
  __syncthreads();
  if(found) atomicOr(&s,1);
  __syncthreads();
  int isf32=s;
  if(blockIdx.x==0 && threadIdx.x==0) *flag=isf32;
  int idx=blockIdx.x*256+threadIdx.x;
  #pragma unroll 1
  for(int i=0;i<25;i++){
    if(idx < a.len[i]){
      float v = isf32 ? ((const float*)a.src[i])[idx]
                      : bf16_to_f32(((const unsigned short*)a.src[i])[idx]);
      dst[a.off[i]+idx]=v;
      return;
    }
    idx -= a.len[i];
  }
}

// ---------- sort: counting-sort word indices by descending length ----------
__global__ void k_sort(const int* __restrict__ lensp, int* __restrict__ ord){
  __shared__ int hist[64];
  __shared__ int base[64];
  int tid=threadIdx.x;
  if(tid<64) hist[tid]=0;
  __syncthreads();
  for(int i=tid;i<NW;i+=256) atomicAdd(&hist[48-lensp[i]],1);
  __syncthreads();
  if(tid==0){ int s=0; for(int b=0;b<64;b++){ base[b]=s; s+=hist[b]; } }
  __syncthreads();
  for(int i=tid;i<NW;i+=256){
    int b=48-lensp[i];
    int pos=atomicAdd(&base[b],1);
    ord[pos]=i;
  }
}

// ---------- prep: pack wpfrag / pfrag / mfrag / biasv / L0 ----------
__global__ void k_prep(const float* __restrict__ cw, unsigned short* __restrict__ wpfrag,
                       unsigned short* __restrict__ pfrag, unsigned short* __restrict__ mfrag,
                       float* __restrict__ biasv){
  int idx=blockIdx.x*256+threadIdx.x;
  if(idx<32768){
    int j=idx&7, lane=(idx>>3)&63, nt=(idx>>9)&7, ks=idx>>12;
    int nl=lane&15, q=lane>>4;
    float v = cw[C_WWP + (nt*16+nl)*256 + ks*32 + q*8 + j] * (2.f*LOG2E);
    wpfrag[idx]=f32_to_h16u(v);
  } else if(idx<65536){
    int i=idx-32768;
    int j=i&7, lane=(i>>3)&63, nt=(i>>9)&7, ks=i>>12;
    int nl=lane&15, q=lane>>4;
    float v = cw[C_PWP + (nt*16+nl)*256 + ks*32 + q*8 + j] * (2.f*LOG2E);
    pfrag[i]=f32_to_h16u(v);
  } else if(idx<262144){
    int i=idx-65536;
    int j=i&7, lane=(i>>3)&63, t2=i>>9;
    int nt=t2%48, ks=t2/48;
    int n=nt*16+(lane&15), k=ks*32+(lane>>4)*8+j;
    int gate = (n<G3)? n : n-G3;
    float sc = (gate<256)? -LOG2E : 2.f*LOG2E;
    float v = ((n<G3)? cw[C_MWIH_F + n*256 + k] : cw[C_MWIH_B + (n-G3)*256 + k]) * sc;
    mfrag[i]=f32_to_h16u(v);
  } else if(idx<262912){
    int i=idx-262144;
    int dir=i/384, g=i-384*(i/384);
    float b = cw[(dir?C_MBIH_B:C_MBIH_F)+g] + ((g<256)? cw[(dir?C_MBHH_B:C_MBHH_F)+g] : 0.f);
    biasv[i] = b * ((g<256)? -LOG2E : 2.f*LOG2E);
  } else if(idx==262912){
    // L0: word-attention logit of an all-zero out row
    float a=0.f;
    for(int c=0;c<128;c++) a += tanh2(cw[C_WBP+c]*(2.f*LOG2E))*cw[C_WCTX+c];
    biasv[768]=a;
  }
}

// ---------- prepx: x-gate table via MFMA ----------
__global__ __launch_bounds__(512) void k_prepx(const float* __restrict__ cw,
                                               float4* __restrict__ xgt4){
  int tid=threadIdx.x;
  int w=tid>>6, L=tid&63, nl=L&15, q=L>>4;
  int mchunk=blockIdx.x, dir=blockIdx.y;
  const float* Wih=cw+(dir?C_CWIH_B:C_CWIH_F);
  const float* bih=cw+(dir?C_CBIH_B:C_CBIH_F);
  const float* bhh=cw+(dir?C_CBHH_B:C_CBHH_F);
  int c16=w*16+nl;

  f16x8 bw[3][2];
  #pragma unroll
  for(int i=0;i<3;i++){
    int n=(w+8*i)*16+nl;
    const float* wr=Wih + n*EDIM;
    #pragma unroll
    for(int ks=0;ks<2;ks++){
      const float4* p=(const float4*)(wr + ks*32 + q*8);
      float4 v0=p[0], v1=p[1];
      f16x8 f;
      f[0]=(_Float16)v0.x; f[1]=(_Float16)v0.y; f[2]=(_Float16)v0.z; f[3]=(_Float16)v0.w;
      f[4]=(_Float16)v1.x; f[5]=(_Float16)v1.y; f[6]=(_Float16)v1.z; f[7]=(_Float16)v1.w;
      bw[i][ks]=f;
    }
  }
  float br=bih[c16]+bhh[c16];
  float bz=bih[128+c16]+bhh[128+c16];
  float bn=bih[256+c16];

  #pragma unroll
  for(int mt=0;mt<2;mt++){
    int ch=mchunk*32+mt*16+nl;
    f32x4 ar={0,0,0,0}, az={0,0,0,0}, an={0,0,0,0};
    #pragma unroll
    for(int ks=0;ks<2;ks++){
      const float4* p=(const float4*)(cw + C_EMB + ch*EDIM + ks*32 + q*8);
      float4 v0=p[0], v1=p[1];
      f16x8 a;
      a[0]=(_Float16)v0.x; a[1]=(_Float16)v0.y; a[2]=(_Float16)v0.z; a[3]=(_Float16)v0.w;
      a[4]=(_Float16)v1.x; a[5]=(_Float16)v1.y; a[6]=(_Float16)v1.z; a[7]=(_Float16)v1.w;
      ar=mfma16(a,bw[0][ks],ar); az=mfma16(a,bw[1][ks],az); an=mfma16(a,bw[2][ks],an);
    }
    #pragma unroll
    for(int r=0;r<4;r++){
      int chr=mchunk*32+mt*16+q*4+r;
      xgt4[dir*32768 + chr*128 + c16] =
        make_float4((ar[r]+br)*(-LOG2E), (az[r]+bz)*(-LOG2E), (an[r]+bn)*(2.f*LOG2E), 0.f);
    }
  }
}

// ---------- fused char BiGRU + attention pool (flash-style online softmax) ----------
// 16 seqs/block (length-sorted), 8 waves. Phase dir=0: fwd GRU, store of (f16).
// Phase dir=1: bwd GRU; per step reload of_t (L2-hot, same block wrote it), build
// out row in LDS, proj-MFMA + tanh logits, online-softmax accumulate N,m,d.
__global__ __launch_bounds__(512,4) void k_char(const int* __restrict__ chars,
    const int* __restrict__ lensp, const int* __restrict__ ord,
    const float* __restrict__ cw, const float4* __restrict__ xgt4,
    const unsigned short* __restrict__ wpfrag, const float* __restrict__ bp,
    const float* __restrict__ ctxv, const float* __restrict__ L0p,
    _Float16* __restrict__ chout, _Float16* __restrict__ wordsF16){
  int tid=threadIdx.x;
  int w=tid>>6, L=tid&63, nl=L&15, q=L>>4;
  int seq0=blockIdx.x*16;
  int c16=w*16+nl;

  __shared__ int sordS[16];
  __shared__ int lenS[16];
  __shared__ int cidT[CLEN][16];
  __shared__ __align__(16) _Float16 hbuf[2][16][136];
  __shared__ __align__(16) _Float16 obuf[16][264];   // [of | ob] per seq
  __shared__ float Nacc[16][264];
  __shared__ float redl[16][8];
  __shared__ float mS[16], dS[16], aS[16], eS[16];

  if(tid<16) sordS[tid]=ord[seq0+tid];
  __syncthreads();
  if(tid<16) lenS[tid]=lensp[sordS[tid]];
  for(int i=tid;i<16*CLEN;i+=512){ int t=i>>4, s=i&15; cidT[t][s]=chars[sordS[s]*CLEN+t]; }
  __syncthreads();

  int maxlen=1;
  #pragma unroll 1
  for(int s=0;s<16;s++) maxlen=max(maxlen,lenS[s]);
  int lenq[4];
  #pragma unroll
  for(int r=0;r<4;r++) lenq[r]=lenS[q*4+r];
  int sw=tid>>5, aw=tid&31;
  int lenp=lenS[sw];
  size_t sqbase=(size_t)sordS[sw]*48*128;
  float bpw=bp[c16]*(2.f*LOG2E), cvw=ctxv[c16];
  float L0=*L0p;

  #pragma unroll 1
  for(int dir=0; dir<2; ++dir){
    const float* Whh=cw+(dir?C_CWHH_B:C_CWHH_F);
    const float* bhh=cw+(dir?C_CBHH_B:C_CBHH_F);
    const float4* xg4 = xgt4 + (dir<<15);
    f16x8 bh[3][4];
    const float wsc0 = -LOG2E, wsc2 = 2.f*LOG2E;
    #pragma unroll
    for(int i=0;i<3;i++){
      int n=(w+8*i)*16+nl;
      const float* wr=Whh + n*HDIM;
      float sc = (i==2)? wsc2 : wsc0;
      #pragma unroll
      for(int c=0;c<4;c++){
        const float4* p=(const float4*)(wr + c*32 + q*8);
        float4 v0=p[0], v1=p[1];
        f16x8 f;
        f[0]=(_Float16)(v0.x*sc); f[1]=(_Float16)(v0.y*sc); f[2]=(_Float16)(v0.z*sc); f[3]=(_Float16)(v0.w*sc);
        f[4]=(_Float16)(v1.x*sc); f[5]=(_Float16)(v1.y*sc); f[6]=(_Float16)(v1.z*sc); f[7]=(_Float16)(v1.w*sc);
        bh[i][c]=f;
      }
    }
    float bias_hn=bhh[256+c16]*(2.f*LOG2E);
    f16x8 wfr[8];
    if(dir){
      const uint4* wp4=(const uint4*)wpfrag;
      #pragma unroll
      for(int ks=0;ks<8;ks++){
        uint4 u=wp4[(ks*8+w)*64+L];
        __builtin_memcpy(&wfr[ks],&u,16);
      }
    }
    __syncthreads();   // protect hbuf zeroing vs previous phase tail reads
    for(int i=tid;i<16*136;i+=512){ ((uint32_t*)&hbuf[0][0][0])[i&0xffff]=0u; }
    // zero both hbuf buffers (2*16*136 f16 = 2176 u32)
    for(int i=tid;i<2176;i+=512) ((uint32_t*)&hbuf[0][0][0])[i]=0u;
    if(dir){
      for(int i=tid;i<16*264;i+=512) ((float*)&Nacc[0][0])[i]=0.f;
      if(tid<16){ mS[tid]=-1e30f; dS[tid]=0.f; }
    }
    float hreg[4]={0.f,0.f,0.f,0.f};
    __syncthreads();

    float4 pf[4];
    {
      int t0 = dir ? maxlen-1 : 0;
      int4 c4=*(const int4*)&cidT[t0][q*4];
      pf[0]=xg4[c4.x*128+c16]; pf[1]=xg4[c4.y*128+c16];
      pf[2]=xg4[c4.z*128+c16]; pf[3]=xg4[c4.w*128+c16];
    }
    _Float16* wpo = chout + sqbase + 4*aw;   // fwd writer

    #pragma unroll 1
    for(int step=0; step<maxlen; ++step){
      int t = dir ? maxlen-1-step : step;
      int p = step&1;
      float4 qf[4];
      bool havepf = (step+1 < maxlen);
      if(havepf){
        int tn = dir ? maxlen-2-step : step+1;
        int4 c4=*(const int4*)&cidT[tn][q*4];
        qf[0]=xg4[c4.x*128+c16]; qf[1]=xg4[c4.y*128+c16];
        qf[2]=xg4[c4.z*128+c16]; qf[3]=xg4[c4.w*128+c16];
      }
      // stage of_t into obuf[:,0:128] (bwd only); pads -> zero
      if(dir && tid<256){
        int s=tid>>4, u=tid&15;
        uint4 v=make_uint4(0,0,0,0);
        if(t<lenS[s]) v=((const uint4*)(chout + ((size_t)sordS[s]*48+t)*128))[u];
        *(uint4*)&obuf[s][u*8]=v;
      }
      // ---- GRU MFMA ----
      f32x4 ra={0,0,0,0}, rb={0,0,0,0}, za={0,0,0,0}, zb={0,0,0,0};
      f32x4 ha={bias_hn,bias_hn,bias_hn,bias_hn}, hb={0,0,0,0};
      const _Float16* hrow=&hbuf[p][nl][0];
      f16x8 af0=*(const f16x8*)(hrow + 0*32 + q*8);
      f16x8 af1=*(const f16x8*)(hrow + 1*32 + q*8);
      f16x8 af2=*(const f16x8*)(hrow + 2*32 + q*8);
      f16x8 af3=*(const f16x8*)(hrow + 3*32 + q*8);
      ra=mfma16(af0,bh[0][0],ra); za=mfma16(af0,bh[1][0],za); ha=mfma16(af0,bh[2][0],ha);
      rb=mfma16(af1,bh[0][1],rb); zb=mfma16(af1,bh[1][1],zb); hb=mfma16(af1,bh[2][1],hb);
      ra=mfma16(af2,bh[0][2],ra); za=mfma16(af2,bh[1][2],za); ha=mfma16(af2,bh[2][2],ha);
      rb=mfma16(af3,bh[0][3],rb); zb=mfma16(af3,bh[1][3],zb); hb=mfma16(af3,bh[2][3],hb);
      f32x4 accr=ra+rb, accz=za+zb, a2h=ha+hb;
      #pragma unroll
      for(int r=0;r<4;r++){
        float rg=sig2(accr[r]+pf[r].x);
        float zg=sig2(accz[r]+pf[r].y);
        float nn=tanh2(fmaf(rg,a2h[r],pf[r].z));
        float hnew=fmaf(zg,hreg[r]-nn,nn);
        bool valid = t < lenq[r];
        float hv = valid ? hnew : hreg[r];
        hreg[r]=hv;
        hbuf[p^1][q*4+r][c16]=(_Float16)hv;
        if(dir) obuf[q*4+r][128+c16] = valid ? (_Float16)hnew : (_Float16)0.f;
      }
      __syncthreads();   // S1: hbuf[p^1] + obuf complete
      if(!dir){
        if(t<lenp){
          uint2 d=*(const uint2*)&hbuf[p^1][sw][4*aw];
          *(uint2*)(wpo + (size_t)t*128) = d;
        }
      } else {
        // ---- proj MFMA: tile [16 seqs][16 cols of wave w], K=256 ----
        f32x4 pa={0,0,0,0};
        #pragma unroll
        for(int ks=0;ks<8;ks++){
          f16x8 af=*(const f16x8*)&obuf[nl][ks*32+q*8];
          pa=mfma16(af,wfr[ks],pa);
        }
        #pragma unroll
        for(int r=0;r<4;r++){
          float v=tanh2(pa[r]+bpw)*cvw;
          v+=__shfl_xor(v,1,64); v+=__shfl_xor(v,2,64);
          v+=__shfl_xor(v,4,64); v+=__shfl_xor(v,8,64);
          if(nl==0) redl[q*4+r][w]=v;
        }
        __syncthreads(); // S2
        if(tid<16){
          float l=redl[tid][0]+redl[tid][1]+redl[tid][2]+redl[tid][3]
                 +redl[tid][4]+redl[tid][5]+redl[tid][6]+redl[tid][7];
          float m0=mS[tid];
          float m1=fmaxf(m0,l);
          float al=exp2_fast((m0-m1)*LOG2E);
          float e =exp2_fast((l -m1)*LOG2E);
          dS[tid]=dS[tid]*al+e; mS[tid]=m1; aS[tid]=al; eS[tid]=e;
        }
        __syncthreads(); // S3
        {
          int s=tid>>5; int cc=(tid&31)*8;
          float al=aS[s], e=eS[s];
          f16x8 ov=*(const f16x8*)&obuf[s][cc];
          #pragma unroll
          for(int k2=0;k2<8;k2++) Nacc[s][cc+k2]=fmaf(Nacc[s][cc+k2],al,e*(float)ov[k2]);
        }
        __syncthreads(); // S4: obuf free for next staging
      }
      #pragma unroll
      for(int r=0;r<4;r++) pf[r]=qf[r];
    }
  }
  // ---- finalize: virtual pad rows t in [maxlen,48) with logit L0, out=0 ----
  if(tid<16){
    float m0=mS[tid];
    float m1=fmaxf(m0,L0);
    float al=exp2_fast((m0-m1)*LOG2E);
    float d=dS[tid]*al + (float)(48-maxlen)*exp2_fast((L0-m1)*LOG2E);
    aS[tid]=al*rcp_fast(d);
  }
  __syncthreads();
  {
    int s=tid>>5; int cc=(tid&31)*8;
    float sc=aS[s];
    f16x8 o;
    #pragma unroll
    for(int k2=0;k2<8;k2++) o[k2]=(_Float16)(Nacc[s][cc+k2]*sc);
    uint4 u; __builtin_memcpy(&u,&o,16);
    *(uint4*)&wordsF16[(size_t)sordS[s]*256+cc]=u;
  }
}

// ---------- fused message GRU: MFMA xg-GEMM prologue + recurrent loop ----------
__global__ __launch_bounds__(384) void k_msggru(const float* __restrict__ cw,
    const _Float16* __restrict__ wordsF16, const unsigned short* __restrict__ mfrag,
    const float* __restrict__ biasv, unsigned short* __restrict__ msg_out){
  int dir=blockIdx.y, b=blockIdx.x, tid=threadIdx.x;
  int w=tid>>6, lane=tid&63, nl=lane&15, q=lane>>4;

  __shared__ _Float16 xgL[64][392];
  __shared__ __align__(16) _Float16 hh[HDIM];
  __shared__ float rr[HDIM], zz[HDIM], xns[HDIM], hns[HDIM];

  {
    int ntb = dir*24 + w*4;
    const uint4* mf4=(const uint4*)mfrag;
    const uint4* wv=(const uint4*)wordsF16;
    f32x4 acc[4][4];
    #pragma unroll
    for(int mt=0;mt<4;mt++)
      #pragma unroll
      for(int i=0;i<4;i++) acc[mt][i]=(f32x4){0,0,0,0};
    #pragma unroll
    for(int ks=0;ks<8;ks++){
      f16x8 bf[4];
      #pragma unroll
      for(int i=0;i<4;i++){
        uint4 u=mf4[((ks*48 + ntb+i)*64 + lane)];
        __builtin_memcpy(&bf[i],&u,16);
      }
      #pragma unroll
      for(int mt=0;mt<4;mt++){
        uint4 u=wv[((size_t)b*64 + mt*16 + nl)*32 + ks*4 + q];
        f16x8 av; __builtin_memcpy(&av,&u,16);
        #pragma unroll
        for(int i=0;i<4;i++) acc[mt][i]=mfma16(av,bf[i],acc[mt][i]);
      }
    }
    float bi[4];
    #pragma unroll
    for(int i=0;i<4;i++) bi[i]=biasv[dir*384 + (w*4+i)*16+nl];
    #pragma unroll
    for(int mt=0;mt<4;mt++)
      #pragma unroll
      for(int i=0;i<4;i++){
        int g=(w*4+i)*16+nl;
        #pragma unroll
        for(int r=0;r<4;r++)
          xgL[mt*16+q*4+r][g]=(_Float16)(acc[mt][i][r]+bi[i]);
      }
  }

  const float* Whh=cw+(dir?C_MWHH_B:C_MWHH_F);
  const float* bhh=cw+(dir?C_MBHH_B:C_MBHH_F);
  uint32_t whh[64];
  {
    float sc = (tid<256) ? -LOG2E : 2.f*LOG2E;
    const float4* h4=(const float4*)(Whh + tid*HDIM);
    #pragma unroll
    for(int i=0;i<32;i++){ float4 v=h4[i]; whh[2*i]=pack_h2(v.x*sc,v.y*sc); whh[2*i+1]=pack_h2(v.z*sc,v.w*sc); }
  }
  float ha0 = (tid>=256) ? bhh[tid]*(2.f*LOG2E) : 0.f;
  if(tid<64) ((uint32_t*)hh)[tid]=0u;
  float hreg=0.f;
  __syncthreads();
  int j=tid&127, gt=tid>>7;
  for(int step=0;step<WRD;step++){
    int wt = dir ? (WRD-1-step) : step;
    float xacc = (float)xgL[wt][tid];
    float ha=ha0;
    const uint4* hp=(const uint4*)hh;
    #pragma unroll
    for(int qq=0;qq<16;qq++){ uint4 v=hp[qq];
      ha=dot2(whh[4*qq+0],v.x,ha); ha=dot2(whh[4*qq+1],v.y,ha);
      ha=dot2(whh[4*qq+2],v.z,ha); ha=dot2(whh[4*qq+3],v.w,ha); }
    if(gt==0)      rr[j]=sig2(xacc+ha);
    else if(gt==1) zz[j]=sig2(xacc+ha);
    else { xns[j]=xacc; hns[j]=ha; }
    __syncthreads();
    if(tid<HDIM){
      float r=rr[tid], z=zz[tid];
      float nn=tanh2(fmaf(r,hns[tid],xns[tid]));
      float hnew=fmaf(z,hreg-nn,nn);
      hreg=hnew;
      hh[tid]=(_Float16)hnew;
      msg_out[(size_t)(b*WRD+wt)*256 + dir*HDIM + tid]=f32_to_h16u(hnew);
    }
    __syncthreads();
  }
}

// ---------- message attention pool via MFMA + fused final linear ----------
__global__ __launch_bounds__(256) void k_mpool(const unsigned short* __restrict__ outp,
    const unsigned short* __restrict__ pfrag, const float* __restrict__ bp,
    const float* __restrict__ ctxv,
    const float* __restrict__ Wout, const float* __restrict__ bout,
    void* dout, const int* __restrict__ flag){
  int n=blockIdx.x, tid=threadIdx.x;
  int w=tid>>6, lane=tid&63, nl=lane&15, q=lane>>4;
  __shared__ __align__(16) _Float16 sa[64][264];
  __shared__ float redl[64][4];
  __shared__ float att[64];
  __shared__ float msgv[256];

  uint4 bfr[2][8];
  const uint4* pf4=(const uint4*)pfrag;
  #pragma unroll
  for(int ks=0;ks<8;ks++){
    bfr[0][ks]=pf4[(ks*8+2*w  )*64+lane];
    bfr[1][ks]=pf4[(ks*8+2*w+1)*64+lane];
  }
  {
    const uint4* src=(const uint4*)(outp + (size_t)n*64*256);
    #pragma unroll
    for(int i=0;i<8;i++){
      int ii=tid+256*i; int row=ii>>5, c16=ii&31;
      *(uint4*)&sa[row][c16*8]=src[ii];
    }
  }
  __syncthreads();

  f32x4 acc[4][2];
  #pragma unroll
  for(int mt=0;mt<4;mt++){ acc[mt][0]=(f32x4){0,0,0,0}; acc[mt][1]=(f32x4){0,0,0,0}; }
  #pragma unroll
  for(int ks=0;ks<8;ks++){
    f16x8 b0,b1;
    __builtin_memcpy(&b0,&bfr[0][ks],16);
    __builtin_memcpy(&b1,&bfr[1][ks],16);
    #pragma unroll
    for(int mt=0;mt<4;mt++){
      f16x8 af=*(const f16x8*)&sa[mt*16+nl][ks*32+q*8];
      acc[mt][0]=mfma16(af,b0,acc[mt][0]);
      acc[mt][1]=mfma16(af,b1,acc[mt][1]);
    }
  }
  int c0=(2*w)*16+nl, c1=c0+16;
  float bp0=bp[c0]*(2.f*LOG2E), bp1=bp[c1]*(2.f*LOG2E);
  float cv0=ctxv[c0], cv1=ctxv[c1];
  #pragma unroll
  for(int mt=0;mt<4;mt++){
    #pragma unroll
    for(int r=0;r<4;r++){
      float v=tanh2(acc[mt][0][r]+bp0)*cv0 + tanh2(acc[mt][1][r]+bp1)*cv1;
      v+=__shfl_xor(v,1,64); v+=__shfl_xor(v,2,64);
      v+=__shfl_xor(v,4,64); v+=__shfl_xor(v,8,64);
      if(nl==0) redl[mt*16+q*4+r][w]=v;
    }
  }
  __syncthreads();
  if(tid<64){
    float v=redl[tid][0]+redl[tid][1]+redl[tid][2]+redl[tid][3];
    float mx=wave_max(v);
    float e=exp2_fast((v-mx)*LOG2E);
    float s=wave_sum(e);
    att[tid]=e*rcp_fast(s);
  }
  __syncthreads();
  float a=0.f;
  #pragma unroll 1
  for(int t=0;t<64;t++) a=fmaf(att[t],(float)sa[t][tid],a);
  msgv[tid]=a;
  if(*flag){ ((float*)dout)[1024 + n*256 + tid]=a; }
  else { ((unsigned short*)dout)[1024 + n*256 + tid]=f32_to_bf16(a); }
  __syncthreads();
  if(tid<OUTD){
    float acc2=bout[tid];
    #pragma unroll 1
    for(int k=0;k<256;k++) acc2=fmaf(msgv[k], Wout[tid*256+k], acc2);
    if(*flag) ((float*)dout)[n*OUTD+tid]=acc2;
    else ((unsigned short*)dout)[n*OUTD+tid]=f32_to_bf16(acc2);
  }
}

extern "C" void kernel_launch(void* const* d_in, const int* in_sizes, int n_in,
                              void* d_out, int out_size, void* d_ws, size_t ws_size,
                              hipStream_t stream){
  (void)in_sizes; (void)n_in; (void)out_size; (void)ws_size;
  char* ws=(char*)d_ws;
  int* flag=(int*)(ws+OFF_FLAG);
  float* canon=(float*)(ws+OFF_CANON);
  unsigned short* wpfrag=(unsigned short*)(ws+OFF_WPFRAG);
  unsigned short* pfrag=(unsigned short*)(ws+OFF_PFRAG);
  unsigned short* mfrag=(unsigned short*)(ws+OFF_MFRAG);
  float* biasv=(float*)(ws+OFF_BIASV);
  int* ord=(int*)(ws+OFF_ORD);
  float4* xgt4=(float4*)(ws+OFF_XGT4);
  _Float16* wordsF16=(_Float16*)(ws+OFF_WORDS);
  unsigned short* msgout=(unsigned short*)(ws+OFF_MSGOUT);
  _Float16* chout=(_Float16*)(ws+OFF_CHOUT);
  const int* chars=(const int*)d_in[0];
  const int* lensp=(const int*)d_in[1];

  ConvArgs ca;
  static const int clen_[25]={16384,24576,49152,384,384,24576,49152,384,384,
                              98304,49152,768,768,98304,49152,768,768,
                              32768,128,128,32768,128,128,2048,8};
  int off=0;
  for(int i=0;i<25;i++){ ca.src[i]=d_in[i+2]; ca.len[i]=clen_[i]; ca.off[i]=off; off+=clen_[i]; }
  hipLaunchKernelGGL(k_convert, dim3((C_TOTAL+255)/256), dim3(256), 0, stream, ca, flag, canon);
  hipLaunchKernelGGL(k_sort, dim3(1), dim3(256), 0, stream, lensp, ord);
  hipLaunchKernelGGL(k_prep, dim3(1028), dim3(256), 0, stream, canon, wpfrag, pfrag, mfrag, biasv);
  hipLaunchKernelGGL(k_prepx, dim3(8,2), dim3(512), 0, stream, canon, xgt4);
  hipLaunchKernelGGL(k_char, dim3(NW/16), dim3(512), 0, stream, chars, lensp, ord,
                     canon, xgt4, wpfrag, canon+C_WBP, canon+C_WCTX, biasv+768,
                     chout, wordsF16);
  hipLaunchKernelGGL(k_msggru, dim3(BATCH,2), dim3(384), 0, stream, canon, wordsF16, mfrag, biasv, msgout);
  hipLaunchKernelGGL(k_mpool, dim3(BATCH), dim3(256), 0, stream, msgout, pfrag,
                     canon+C_PBP, canon+C_PCTX,
                     canon+C_WOUT, canon+C_BOUT, d_out, flag);
}

// Round 10
// 469.065 us; speedup vs baseline: 1.7605x; 1.7605x over previous
//
#include <hip/hip_runtime.h>
#include <stdint.h>
#include <stddef.h>

#define NCH   256
#define EDIM  64
#define HDIM  128
#define G3    384
#define BATCH 128
#define WRD   64
#define CLEN  48
#define NW    8192
#define OUTD  8

#define LOG2E 1.44269504088896f

// ---- canonical fp32 weight offsets (element units) ----
#define C_EMB     0
#define C_CWIH_F  16384
#define C_CWHH_F  40960
#define C_CBIH_F  90112
#define C_CBHH_F  90496
#define C_CWIH_B  90880
#define C_CWHH_B  115456
#define C_CBIH_B  164608
#define C_CBHH_B  164992
#define C_MWIH_F  165376
#define C_MWHH_F  263680
#define C_MBIH_F  312832
#define C_MBHH_F  313600
#define C_MWIH_B  314368
#define C_MWHH_B  412672
#define C_MBIH_B  461824
#define C_MBHH_B  462592
#define C_WWP     463360
#define C_WBP     496128
#define C_WCTX    496256
#define C_PWP     496384
#define C_PBP     529152
#define C_PCTX    529280
#define C_WOUT    529408
#define C_BOUT    531456
#define C_TOTAL   531464

// ---- ws byte offsets ----
#define OFF_FLAG    0u
#define OFF_CANON   1024u
#define OFF_WPFRAG  (4u*1024u*1024u)               // 32768 f16 = 64 KB
#define OFF_PFRAG   (4u*1024u*1024u + 65536u)      // 32768 f16 = 64 KB
#define OFF_MFRAG   (4u*1024u*1024u + 131072u)     // 196608 f16 = 384 KB
#define OFF_BIASV   (4u*1024u*1024u + 524288u)     // 768 f32
#define OFF_ORD     (4u*1024u*1024u + 532480u)     // 8192 int = 32 KB
#define OFF_XGT4    5111808u                        // 65536 float4 = 1 MB
#define OFF_WORDS   35651584u                       // 8192*256 f16 = 4 MB
#define OFF_MSGOUT  47185920u
#define OFF_CHOUT   54525952u

typedef _Float16 h2v __attribute__((ext_vector_type(2)));
typedef _Float16 f16x8 __attribute__((ext_vector_type(8)));
typedef float f32x4 __attribute__((ext_vector_type(4)));

__device__ __forceinline__ float bf16_to_f32(unsigned short u){
  union{unsigned int i;float f;}v; v.i=((unsigned int)u)<<16; return v.f;
}
__device__ __forceinline__ unsigned short f32_to_bf16(float f){
  union{float f;unsigned int i;}v; v.f=f;
  unsigned int u=v.i; unsigned int r=(u + 0x7fffu + ((u>>16)&1u))>>16;
  return (unsigned short)r;
}
__device__ __forceinline__ uint32_t pack_h2(float x,float y){
  h2v h; h[0]=(_Float16)x; h[1]=(_Float16)y; uint32_t u; __builtin_memcpy(&u,&h,4); return u;
}
__device__ __forceinline__ unsigned short f32_to_h16u(float f){
  _Float16 h=(_Float16)f; unsigned short u; __builtin_memcpy(&u,&h,2); return u;
}
__device__ __forceinline__ float dot2(uint32_t a, uint32_t b, float c){
#if __has_builtin(__builtin_amdgcn_fdot2)
  h2v av,bv; __builtin_memcpy(&av,&a,4); __builtin_memcpy(&bv,&b,4);
  return __builtin_amdgcn_fdot2(av,bv,c,false);
#else
  h2v av,bv; __builtin_memcpy(&av,&a,4); __builtin_memcpy(&bv,&b,4);
  return c + (float)av[0]*(float)bv[0] + (float)av[1]*(float)bv[1];
#endif
}
__device__ __forceinline__ float exp2_fast(float x){
#if __has_builtin(__builtin_amdgcn_exp2f)
  return __builtin_amdgcn_exp2f(x);
#else
  return exp2f(x);
#endif
}
__device__ __forceinline__ float rcp_fast(float x){
#if __has_builtin(__builtin_amdgcn_rcpf)
  return __builtin_amdgcn_rcpf(x);
#else
  return 1.f/x;
#endif
}
// sigmoid(x) given s = -log2e*x ; tanh(y) given u = 2*log2e*y
__device__ __forceinline__ float sig2(float s){ return rcp_fast(1.f+exp2_fast(s)); }
__device__ __forceinline__ float tanh2(float u){ return fmaf(-2.f, rcp_fast(exp2_fast(u)+1.f), 1.f); }
__device__ __forceinline__ float wave_sum(float v){
  #pragma unroll
  for(int m=32;m>=1;m>>=1) v += __shfl_xor(v,m,64);
  return v;
}
__device__ __forceinline__ float wave_max(float v){
  #pragma unroll
  for(int m=32;m>=1;m>>=1) v = fmaxf(v,__shfl_xor(v,m,64));
  return v;
}
__device__ __forceinline__ f32x4 mfma16(f16x8 a, f16x8 b, f32x4 c){
  return __builtin_amdgcn_mfma_f32_16x16x32_f16(a, b, c, 0, 0, 0);
}

struct ConvArgs { const void* src[25]; int len[25]; int off[25]; };

// ---------- convert with inline dtype sniff ----------
__global__ void k_convert(ConvArgs a, int* __restrict__ flag, float* __restrict__ dst){
  const unsigned short* u=(const unsigned short*)a.src[0];
  int found=0;
  for(int i=threadIdx.x;i<2048;i+=256){ float v=bf16_to_f32(u[i]); if(fabsf(v)>8.f) found=1; }
  __shared__ int s;
  if(threadIdx.x==0) s=0;
  __syncthreads();
  if(found) atomicOr(&s,1);
  __syncthreads();
  int isf32=s;
  if(blockIdx.x==0 && threadIdx.x==0) *flag=isf32;
  int idx=blockIdx.x*256+threadIdx.x;
  #pragma unroll 1
  for(int i=0;i<25;i++){
    if(idx < a.len[i]){
      float v = isf32 ? ((const float*)a.src[i])[idx]
                      : bf16_to_f32(((const unsigned short*)a.src[i])[idx]);
      dst[a.off[i]+idx]=v;
      return;
    }
    idx -= a.len[i];
  }
}

// ---------- sort: counting-sort word indices by descending length ----------
__global__ void k_sort(const int* __restrict__ lensp, int* __restrict__ ord){
  __shared__ int hist[64];
  __shared__ int base[64];
  int tid=threadIdx.x;
  if(tid<64) hist[tid]=0;
  __syncthreads();
  for(int i=tid;i<NW;i+=256) atomicAdd(&hist[48-lensp[i]],1);
  __syncthreads();
  if(tid==0){ int s=0; for(int b=0;b<64;b++){ base[b]=s; s+=hist[b]; } }
  __syncthreads();
  for(int i=tid;i<NW;i+=256){
    int b=48-lensp[i];
    int pos=atomicAdd(&base[b],1);
    ord[pos]=i;
  }
}

// ---------- prep: pack wpfrag / pfrag / mfrag / biasv ----------
__global__ void k_prep(const float* __restrict__ cw, unsigned short* __restrict__ wpfrag,
                       unsigned short* __restrict__ pfrag, unsigned short* __restrict__ mfrag,
                       float* __restrict__ biasv){
  int idx=blockIdx.x*256+threadIdx.x;
  if(idx<32768){
    int j=idx&7, lane=(idx>>3)&63, nt=(idx>>9)&7, ks=idx>>12;
    int nl=lane&15, q=lane>>4;
    float v = cw[C_WWP + (nt*16+nl)*256 + ks*32 + q*8 + j] * (2.f*LOG2E);
    wpfrag[idx]=f32_to_h16u(v);
  } else if(idx<65536){
    int i=idx-32768;
    int j=i&7, lane=(i>>3)&63, nt=(i>>9)&7, ks=i>>12;
    int nl=lane&15, q=lane>>4;
    float v = cw[C_PWP + (nt*16+nl)*256 + ks*32 + q*8 + j] * (2.f*LOG2E);
    pfrag[i]=f32_to_h16u(v);
  } else if(idx<262144){
    int i=idx-65536;
    int j=i&7, lane=(i>>3)&63, t2=i>>9;
    int nt=t2%48, ks=t2/48;
    int n=nt*16+(lane&15), k=ks*32+(lane>>4)*8+j;
    int gate = (n<G3)? n : n-G3;
    float sc = (gate<256)? -LOG2E : 2.f*LOG2E;
    float v = ((n<G3)? cw[C_MWIH_F + n*256 + k] : cw[C_MWIH_B + (n-G3)*256 + k]) * sc;
    mfrag[i]=f32_to_h16u(v);
  } else if(idx<262912){
    int i=idx-262144;
    int dir=i/384, g=i-384*(i/384);
    float b = cw[(dir?C_MBIH_B:C_MBIH_F)+g] + ((g<256)? cw[(dir?C_MBHH_B:C_MBHH_F)+g] : 0.f);
    biasv[i] = b * ((g<256)? -LOG2E : 2.f*LOG2E);
  }
}

// ---------- prepx: x-gate table via MFMA ----------
__global__ __launch_bounds__(512) void k_prepx(const float* __restrict__ cw,
                                               float4* __restrict__ xgt4){
  int tid=threadIdx.x;
  int w=tid>>6, L=tid&63, nl=L&15, q=L>>4;
  int mchunk=blockIdx.x, dir=blockIdx.y;
  const float* Wih=cw+(dir?C_CWIH_B:C_CWIH_F);
  const float* bih=cw+(dir?C_CBIH_B:C_CBIH_F);
  const float* bhh=cw+(dir?C_CBHH_B:C_CBHH_F);
  int c16=w*16+nl;

  f16x8 bw[3][2];
  #pragma unroll
  for(int i=0;i<3;i++){
    int n=(w+8*i)*16+nl;
    const float* wr=Wih + n*EDIM;
    #pragma unroll
    for(int ks=0;ks<2;ks++){
      const float4* p=(const float4*)(wr + ks*32 + q*8);
      float4 v0=p[0], v1=p[1];
      f16x8 f;
      f[0]=(_Float16)v0.x; f[1]=(_Float16)v0.y; f[2]=(_Float16)v0.z; f[3]=(_Float16)v0.w;
      f[4]=(_Float16)v1.x; f[5]=(_Float16)v1.y; f[6]=(_Float16)v1.z; f[7]=(_Float16)v1.w;
      bw[i][ks]=f;
    }
  }
  float br=bih[c16]+bhh[c16];
  float bz=bih[128+c16]+bhh[128+c16];
  float bn=bih[256+c16];

  #pragma unroll
  for(int mt=0;mt<2;mt++){
    int ch=mchunk*32+mt*16+nl;
    f32x4 ar={0,0,0,0}, az={0,0,0,0}, an={0,0,0,0};
    #pragma unroll
    for(int ks=0;ks<2;ks++){
      const float4* p=(const float4*)(cw + C_EMB + ch*EDIM + ks*32 + q*8);
      float4 v0=p[0], v1=p[1];
      f16x8 a;
      a[0]=(_Float16)v0.x; a[1]=(_Float16)v0.y; a[2]=(_Float16)v0.z; a[3]=(_Float16)v0.w;
      a[4]=(_Float16)v1.x; a[5]=(_Float16)v1.y; a[6]=(_Float16)v1.z; a[7]=(_Float16)v1.w;
      ar=mfma16(a,bw[0][ks],ar); az=mfma16(a,bw[1][ks],az); an=mfma16(a,bw[2][ks],an);
    }
    #pragma unroll
    for(int r=0;r<4;r++){
      int chr=mchunk*32+mt*16+q*4+r;
      xgt4[dir*32768 + chr*128 + c16] =
        make_float4((ar[r]+br)*(-LOG2E), (az[r]+bz)*(-LOG2E), (an[r]+bn)*(2.f*LOG2E), 0.f);
    }
  }
}

// ---------- char BiGRU v6: length-sorted (maxlen loop) + pad-row zero-fill epilogue ----------
// Full chout overwrite (valid rows in-loop, pad rows zeroed) keeps the cache economy
// of round 7 while skipping ~49% of MFMA/transcendental work.
__global__ __launch_bounds__(512,4) void k_chargru(const int* __restrict__ chars,
    const int* __restrict__ lensp, const int* __restrict__ ord,
    const float* __restrict__ cw, const float4* __restrict__ xgt4,
    unsigned short* __restrict__ chout){
  int tid=threadIdx.x;
  int w=tid>>6, L=tid&63, nl=L&15, q=L>>4;
  int dir=blockIdx.y;
  int seq0=blockIdx.x*16;
  const float* Whh=cw+(dir?C_CWHH_B:C_CWHH_F);
  const float* bhh=cw+(dir?C_CBHH_B:C_CBHH_F);
  const float4* xg4 = xgt4 + (dir<<15);

  int c16=w*16+nl;
  f16x8 bh[3][4];
  const float wsc[3]={-LOG2E,-LOG2E,2.f*LOG2E};
  #pragma unroll
  for(int i=0;i<3;i++){
    int n=(w+8*i)*16+nl;
    const float* wr=Whh + n*HDIM;
    float sc=wsc[i];
    #pragma unroll
    for(int c=0;c<4;c++){
      const float4* p=(const float4*)(wr + c*32 + q*8);
      float4 v0=p[0], v1=p[1];
      f16x8 f;
      f[0]=(_Float16)(v0.x*sc); f[1]=(_Float16)(v0.y*sc); f[2]=(_Float16)(v0.z*sc); f[3]=(_Float16)(v0.w*sc);
      f[4]=(_Float16)(v1.x*sc); f[5]=(_Float16)(v1.y*sc); f[6]=(_Float16)(v1.z*sc); f[7]=(_Float16)(v1.w*sc);
      bh[i][c]=f;
    }
  }
  float bias_hn=bhh[256+c16]*(2.f*LOG2E);

  __shared__ int sord[16];
  __shared__ int cidT[CLEN][16];
  __shared__ int lenS[16];
  __shared__ __align__(16) _Float16 hbuf[2][16][136];

  if(tid<16) sord[tid]=ord[seq0+tid];
  __syncthreads();
  for(int i=tid;i<16*CLEN;i+=512){ int t=i>>4, s=i&15; cidT[t][s]=chars[sord[s]*CLEN+t]; }
  if(tid<16) lenS[tid]=lensp[sord[tid]];
  for(int i=tid;i<16*136/2;i+=512) ((uint32_t*)&hbuf[0][0][0])[i]=0u;
  __syncthreads();

  int maxlen=1;
  #pragma unroll 1
  for(int s=0;s<16;s++) maxlen=max(maxlen,lenS[s]);
  int lenq[4];
  #pragma unroll
  for(int r=0;r<4;r++) lenq[r]=lenS[q*4+r];
  int sw=tid>>5, aw=tid&31;
  int lenp=lenS[sw];
  int sq=sord[sw];

  float4 pf[4];
  {
    int t0 = dir ? maxlen-1 : 0;
    int4 c4=*(const int4*)&cidT[t0][q*4];
    pf[0]=xg4[c4.x*128+c16]; pf[1]=xg4[c4.y*128+c16];
    pf[2]=xg4[c4.z*128+c16]; pf[3]=xg4[c4.w*128+c16];
  }
  float hreg[4]={0.f,0.f,0.f,0.f};
  unsigned short* wbase = chout + (size_t)sq*CLEN*256 + dir*HDIM + 4*aw;
  unsigned short* wp = wbase + (size_t)(dir?maxlen-1:0)*256;
  int dstep = dir ? -256 : 256;

  for(int step=0; step<maxlen; ++step){
    int t = dir ? maxlen-1-step : step;
    int p = step&1;
    float4 qf[4];
    bool havepf = (step+1 < maxlen);
    if(havepf){
      int tn = dir ? maxlen-2-step : step+1;
      int4 c4=*(const int4*)&cidT[tn][q*4];
      qf[0]=xg4[c4.x*128+c16]; qf[1]=xg4[c4.y*128+c16];
      qf[2]=xg4[c4.z*128+c16]; qf[3]=xg4[c4.w*128+c16];
    }
    f32x4 ra={0,0,0,0}, rb={0,0,0,0}, za={0,0,0,0}, zb={0,0,0,0};
    f32x4 ha={bias_hn,bias_hn,bias_hn,bias_hn}, hb={0,0,0,0};
    const _Float16* hrow=&hbuf[p][nl][0];
    f16x8 af0=*(const f16x8*)(hrow + 0*32 + q*8);
    f16x8 af1=*(const f16x8*)(hrow + 1*32 + q*8);
    f16x8 af2=*(const f16x8*)(hrow + 2*32 + q*8);
    f16x8 af3=*(const f16x8*)(hrow + 3*32 + q*8);
    ra=mfma16(af0,bh[0][0],ra); za=mfma16(af0,bh[1][0],za); ha=mfma16(af0,bh[2][0],ha);
    rb=mfma16(af1,bh[0][1],rb); zb=mfma16(af1,bh[1][1],zb); hb=mfma16(af1,bh[2][1],hb);
    ra=mfma16(af2,bh[0][2],ra); za=mfma16(af2,bh[1][2],za); ha=mfma16(af2,bh[2][2],ha);
    rb=mfma16(af3,bh[0][3],rb); zb=mfma16(af3,bh[1][3],zb); hb=mfma16(af3,bh[2][3],hb);
    f32x4 accr=ra+rb, accz=za+zb, a2h=ha+hb;
    #pragma unroll
    for(int r=0;r<4;r++){
      float rg=sig2(accr[r]+pf[r].x);
      float zg=sig2(accz[r]+pf[r].y);
      float nn=tanh2(fmaf(rg,a2h[r],pf[r].z));
      float hnew=fmaf(zg,hreg[r]-nn,nn);
      bool valid = t < lenq[r];
      float hv = valid ? hnew : hreg[r];
      hreg[r]=hv;
      hbuf[p^1][q*4+r][c16]=(_Float16)hv;
    }
    __syncthreads();
    if(t<lenp){
      uint2 d=*(const uint2*)&hbuf[p^1][sw][4*aw];
      *(uint2*)wp = d;
    }
    wp += dstep;
    if(havepf){
      #pragma unroll
      for(int r=0;r<4;r++) pf[r]=qf[r];
    }
  }
  // ---- pad-row zero-fill: full chout coverage (avoid poisoned-line drain) ----
  #pragma unroll 1
  for(int t=lenp;t<CLEN;t++){
    *(uint2*)(wbase + (size_t)t*256) = make_uint2(0u,0u);
  }
}

// ---------- word attention pool via MFMA (round-7 proven); words output f16 ----------
__global__ __launch_bounds__(256,4) void k_wpool(const unsigned short* __restrict__ chout,
    const unsigned short* __restrict__ wpfrag, const float* __restrict__ bp,
    const float* __restrict__ ctxv, _Float16* __restrict__ wordsF16){
  int n=blockIdx.x, tid=threadIdx.x;
  int w=tid>>6, lane=tid&63, nl=lane&15, q=lane>>4;
  __shared__ __align__(16) _Float16 sa[48][264];
  __shared__ float redl[48][4];
  __shared__ float att[48];

  uint4 bfr[2][8];
  const uint4* wp4=(const uint4*)wpfrag;
  #pragma unroll
  for(int ks=0;ks<8;ks++){
    bfr[0][ks]=wp4[(ks*8+2*w  )*64+lane];
    bfr[1][ks]=wp4[(ks*8+2*w+1)*64+lane];
  }
  {
    const uint4* src=(const uint4*)(chout + (size_t)n*48*256);
    #pragma unroll
    for(int i=0;i<6;i++){
      int ii=tid+256*i; int row=ii>>5, c16=ii&31;
      *(uint4*)&sa[row][c16*8]=src[ii];
    }
  }
  __syncthreads();

  f32x4 acc[3][2];
  #pragma unroll
  for(int mt=0;mt<3;mt++){ acc[mt][0]=(f32x4){0,0,0,0}; acc[mt][1]=(f32x4){0,0,0,0}; }
  #pragma unroll
  for(int ks=0;ks<8;ks++){
    f16x8 b0,b1;
    __builtin_memcpy(&b0,&bfr[0][ks],16);
    __builtin_memcpy(&b1,&bfr[1][ks],16);
    #pragma unroll
    for(int mt=0;mt<3;mt++){
      f16x8 af=*(const f16x8*)&sa[mt*16+nl][ks*32+q*8];
      acc[mt][0]=mfma16(af,b0,acc[mt][0]);
      acc[mt][1]=mfma16(af,b1,acc[mt][1]);
    }
  }
  int c0=(2*w)*16+nl, c1=c0+16;
  float bp0=bp[c0]*(2.f*LOG2E), bp1=bp[c1]*(2.f*LOG2E);
  float cv0=ctxv[c0], cv1=ctxv[c1];
  #pragma unroll
  for(int mt=0;mt<3;mt++){
    #pragma unroll
    for(int r=0;r<4;r++){
      float v=tanh2(acc[mt][0][r]+bp0)*cv0 + tanh2(acc[mt][1][r]+bp1)*cv1;
      v+=__shfl_xor(v,1,64); v+=__shfl_xor(v,2,64);
      v+=__shfl_xor(v,4,64); v+=__shfl_xor(v,8,64);
      if(nl==0) redl[mt*16+q*4+r][w]=v;
    }
  }
  __syncthreads();
  if(tid<64){
    float v=(tid<48)?(redl[tid][0]+redl[tid][1]+redl[tid][2]+redl[tid][3]):-1e30f;
    float mx=wave_max(v);
    float e=(tid<48)?exp2_fast((v-mx)*LOG2E):0.f;
    float s=wave_sum(e);
    if(tid<48) att[tid]=e*rcp_fast(s);
  }
  __syncthreads();
  float a=0.f;
  #pragma unroll 1
  for(int t=0;t<48;t++) a=fmaf(att[t],(float)sa[t][tid],a);
  wordsF16[(size_t)n*256+tid]=(_Float16)a;
}

// ---------- fused message GRU: MFMA xg-GEMM prologue + recurrent loop ----------
__global__ __launch_bounds__(384) void k_msggru(const float* __restrict__ cw,
    const _Float16* __restrict__ wordsF16, const unsigned short* __restrict__ mfrag,
    const float* __restrict__ biasv, unsigned short* __restrict__ msg_out){
  int dir=blockIdx.y, b=blockIdx.x, tid=threadIdx.x;
  int w=tid>>6, lane=tid&63, nl=lane&15, q=lane>>4;

  __shared__ _Float16 xgL[64][392];
  __shared__ __align__(16) _Float16 hh[HDIM];
  __shared__ float rr[HDIM], zz[HDIM], xns[HDIM], hns[HDIM];

  {
    int ntb = dir*24 + w*4;
    const uint4* mf4=(const uint4*)mfrag;
    const uint4* wv=(const uint4*)wordsF16;
    f32x4 acc[4][4];
    #pragma unroll
    for(int mt=0;mt<4;mt++)
      #pragma unroll
      for(int i=0;i<4;i++) acc[mt][i]=(f32x4){0,0,0,0};
    #pragma unroll
    for(int ks=0;ks<8;ks++){
      f16x8 bf[4];
      #pragma unroll
      for(int i=0;i<4;i++){
        uint4 u=mf4[((ks*48 + ntb+i)*64 + lane)];
        __builtin_memcpy(&bf[i],&u,16);
      }
      #pragma unroll
      for(int mt=0;mt<4;mt++){
        uint4 u=wv[((size_t)b*64 + mt*16 + nl)*32 + ks*4 + q];
        f16x8 av; __builtin_memcpy(&av,&u,16);
        #pragma unroll
        for(int i=0;i<4;i++) acc[mt][i]=mfma16(av,bf[i],acc[mt][i]);
      }
    }
    float bi[4];
    #pragma unroll
    for(int i=0;i<4;i++) bi[i]=biasv[dir*384 + (w*4+i)*16+nl];
    #pragma unroll
    for(int mt=0;mt<4;mt++)
      #pragma unroll
      for(int i=0;i<4;i++){
        int g=(w*4+i)*16+nl;
        #pragma unroll
        for(int r=0;r<4;r++)
          xgL[mt*16+q*4+r][g]=(_Float16)(acc[mt][i][r]+bi[i]);
      }
  }

  const float* Whh=cw+(dir?C_MWHH_B:C_MWHH_F);
  const float* bhh=cw+(dir?C_MBHH_B:C_MBHH_F);
  uint32_t whh[64];
  {
    float sc = (tid<256) ? -LOG2E : 2.f*LOG2E;
    const float4* h4=(const float4*)(Whh + tid*HDIM);
    #pragma unroll
    for(int i=0;i<32;i++){ float4 v=h4[i]; whh[2*i]=pack_h2(v.x*sc,v.y*sc); whh[2*i+1]=pack_h2(v.z*sc,v.w*sc); }
  }
  float ha0 = (tid>=256) ? bhh[tid]*(2.f*LOG2E) : 0.f;
  if(tid<64) ((uint32_t*)hh)[tid]=0u;
  float hreg=0.f;
  __syncthreads();
  int j=tid&127, gt=tid>>7;
  for(int step=0;step<WRD;step++){
    int wt = dir ? (WRD-1-step) : step;
    float xacc = (float)xgL[wt][tid];
    float ha=ha0;
    const uint4* hp=(const uint4*)hh;
    #pragma unroll
    for(int qq=0;qq<16;qq++){ uint4 v=hp[qq];
      ha=dot2(whh[4*qq+0],v.x,ha); ha=dot2(whh[4*qq+1],v.y,ha);
      ha=dot2(whh[4*qq+2],v.z,ha); ha=dot2(whh[4*qq+3],v.w,ha); }
    if(gt==0)      rr[j]=sig2(xacc+ha);
    else if(gt==1) zz[j]=sig2(xacc+ha);
    else { xns[j]=xacc; hns[j]=ha; }
    __syncthreads();
    if(tid<HDIM){
      float r=rr[tid], z=zz[tid];
      float nn=tanh2(fmaf(r,hns[tid],xns[tid]));
      float hnew=fmaf(z,hreg-nn,nn);
      hreg=hnew;
      hh[tid]=(_Float16)hnew;
      msg_out[(size_t)(b*WRD+wt)*256 + dir*HDIM + tid]=f32_to_h16u(hnew);
    }
    __syncthreads();
  }
}

// ---------- message attention pool via MFMA + fused final linear ----------
__global__ __launch_bounds__(256) void k_mpool(const unsigned short* __restrict__ outp,
    const unsigned short* __restrict__ pfrag, const float* __restrict__ bp,
    const float* __restrict__ ctxv,
    const float* __restrict__ Wout, const float* __restrict__ bout,
    void* dout, const int* __restrict__ flag){
  int n=blockIdx.x, tid=threadIdx.x;
  int w=tid>>6, lane=tid&63, nl=lane&15, q=lane>>4;
  __shared__ __align__(16) _Float16 sa[64][264];
  __shared__ float redl[64][4];
  __shared__ float att[64];
  __shared__ float msgv[256];

  uint4 bfr[2][8];
  const uint4* pf4=(const uint4*)pfrag;
  #pragma unroll
  for(int ks=0;ks<8;ks++){
    bfr[0][ks]=pf4[(ks*8+2*w  )*64+lane];
    bfr[1][ks]=pf4[(ks*8+2*w+1)*64+lane];
  }
  {
    const uint4* src=(const uint4*)(outp + (size_t)n*64*256);
    #pragma unroll
    for(int i=0;i<8;i++){
      int ii=tid+256*i; int row=ii>>5, c16=ii&31;
      *(uint4*)&sa[row][c16*8]=src[ii];
    }
  }
  __syncthreads();

  f32x4 acc[4][2];
  #pragma unroll
  for(int mt=0;mt<4;mt++){ acc[mt][0]=(f32x4){0,0,0,0}; acc[mt][1]=(f32x4){0,0,0,0}; }
  #pragma unroll
  for(int ks=0;ks<8;ks++){
    f16x8 b0,b1;
    __builtin_memcpy(&b0,&bfr[0][ks],16);
    __builtin_memcpy(&b1,&bfr[1][ks],16);
    #pragma unroll
    for(int mt=0;mt<4;mt++){
      f16x8 af=*(const f16x8*)&sa[mt*16+nl][ks*32+q*8];
      acc[mt][0]=mfma16(af,b0,acc[mt][0]);
      acc[mt][1]=mfma16(af,b1,acc[mt][1]);
    }
  }
  int c0=(2*w)*16+nl, c1=c0+16;
  float bp0=bp[c0]*(2.f*LOG2E), bp1=bp[c1]*(2.f*LOG2E);
  float cv0=ctxv[c0], cv1=ctxv[c1];
  #pragma unroll
  for(int mt=0;mt<4;mt++){
    #pragma unroll
    for(int r=0;r<4;r++){
      float v=tanh2(acc[mt][0][r]+bp0)*cv0 + tanh2(acc[mt][1][r]+bp1)*cv1;
      v+=__shfl_xor(v,1,64); v+=__shfl_xor(v,2,64);
      v+=__shfl_xor(v,4,64); v+=__shfl_xor(v,8,64);
      if(nl==0) redl[mt*16+q*4+r][w]=v;
    }
  }
  __syncthreads();
  if(tid<64){
    float v=redl[tid][0]+redl[tid][1]+redl[tid][2]+redl[tid][3];
    float mx=wave_max(v);
    float e=exp2_fast((v-mx)*LOG2E);
    float s=wave_sum(e);
    att[tid]=e*rcp_fast(s);
  }
  __syncthreads();
  float a=0.f;
  #pragma unroll 1
  for(int t=0;t<64;t++) a=fmaf(att[t],(float)sa[t][tid],a);
  msgv[tid]=a;
  if(*flag){ ((float*)dout)[1024 + n*256 + tid]=a; }
  else { ((unsigned short*)dout)[1024 + n*256 + tid]=f32_to_bf16(a); }
  __syncthreads();
  if(tid<OUTD){
    float acc2=bout[tid];
    #pragma unroll 1
    for(int k=0;k<256;k++) acc2=fmaf(msgv[k], Wout[tid*256+k], acc2);
    if(*flag) ((float*)dout)[n*OUTD+tid]=acc2;
    else ((unsigned short*)dout)[n*OUTD+tid]=f32_to_bf16(acc2);
  }
}

extern "C" void kernel_launch(void* const* d_in, const int* in_sizes, int n_in,
                              void* d_out, int out_size, void* d_ws, size_t ws_size,
                              hipStream_t stream){
  (void)in_sizes; (void)n_in; (void)out_size; (void)ws_size;
  char* ws=(char*)d_ws;
  int* flag=(int*)(ws+OFF_FLAG);
  float* canon=(float*)(ws+OFF_CANON);
  unsigned short* wpfrag=(unsigned short*)(ws+OFF_WPFRAG);
  unsigned short* pfrag=(unsigned short*)(ws+OFF_PFRAG);
  unsigned short* mfrag=(unsigned short*)(ws+OFF_MFRAG);
  float* biasv=(float*)(ws+OFF_BIASV);
  int* ord=(int*)(ws+OFF_ORD);
  float4* xgt4=(float4*)(ws+OFF_XGT4);
  _Float16* wordsF16=(_Float16*)(ws+OFF_WORDS);
  unsigned short* msgout=(unsigned short*)(ws+OFF_MSGOUT);
  unsigned short* chout=(unsigned short*)(ws+OFF_CHOUT);
  const int* chars=(const int*)d_in[0];
  const int* lensp=(const int*)d_in[1];

  ConvArgs ca;
  static const int clen_[25]={16384,24576,49152,384,384,24576,49152,384,384,
                              98304,49152,768,768,98304,49152,768,768,
                              32768,128,128,32768,128,128,2048,8};
  int off=0;
  for(int i=0;i<25;i++){ ca.src[i]=d_in[i+2]; ca.len[i]=clen_[i]; ca.off[i]=off; off+=clen_[i]; }
  hipLaunchKernelGGL(k_convert, dim3((C_TOTAL+255)/256), dim3(256), 0, stream, ca, flag, canon);
  hipLaunchKernelGGL(k_sort, dim3(1), dim3(256), 0, stream, lensp, ord);
  hipLaunchKernelGGL(k_prep, dim3(1028), dim3(256), 0, stream, canon, wpfrag, pfrag, mfrag, biasv);
  hipLaunchKernelGGL(k_prepx, dim3(8,2), dim3(512), 0, stream, canon, xgt4);
  hipLaunchKernelGGL(k_chargru, dim3(NW/16,2), dim3(512), 0, stream, chars, lensp, ord, canon, xgt4, chout);
  hipLaunchKernelGGL(k_wpool, dim3(NW), dim3(256), 0, stream, chout, wpfrag,
                     canon+C_WBP, canon+C_WCTX, wordsF16);
  hipLaunchKernelGGL(k_msggru, dim3(BATCH,2), dim3(384), 0, stream, canon, wordsF16, mfrag, biasv, msgout);
  hipLaunchKernelGGL(k_mpool, dim3(BATCH), dim3(256), 0, stream, msgout, pfrag,
                     canon+C_PBP, canon+C_PCTX,
                     canon+C_WOUT, canon+C_BOUT, d_out, flag);
}